// Round 3
// baseline (252.161 us; speedup 1.0000x reference)
//
#include <hip/hip_runtime.h>
#include <hip/hip_bf16.h>
#include <hip/hip_cooperative_groups.h>

namespace cg = cooperative_groups;

#define C_CLASSES 8192
#define M_ROWS    65536
#define B_ROWS    256
#define D_DIM     2048
#define TEMP_INV  20.0f   // 1 / 0.05

typedef __attribute__((ext_vector_type(8))) short short8;   // 8 bf16 (4 VGPRs)
typedef __attribute__((ext_vector_type(4))) float f32x4;    // MFMA accumulator / vec4

static __device__ __forceinline__ unsigned short f2bf(float x) {
    __hip_bfloat16 h = __float2bfloat16(x);
    return *reinterpret_cast<unsigned short*>(&h);
}

// ============ cooperative prelude: zero + norm + hist + scan + scatter ============
// grid MUST be 256 blocks x 256 threads (one block per input row; 65536 = M threads)
__global__ __launch_bounds__(256) void k_prelude(const int* __restrict__ labels,
                                                 const float* __restrict__ inp,
                                                 int* __restrict__ counts,
                                                 int* __restrict__ offsets,
                                                 int* __restrict__ cursor,
                                                 int* __restrict__ rowidx,
                                                 unsigned short* __restrict__ X,
                                                 float* __restrict__ out) {
    cg::grid_group grid = cg::this_grid();
    int b = blockIdx.x, t = threadIdx.x;
    int g = b * 256 + t;                       // 0..65535

    // ---- phase 0: zero counts / out; L2-normalize input row b -> bf16 X ----
    if (g < C_CLASSES) counts[g] = 0;
    if (g == 0) out[0] = 0.0f;

    {
        const f32x4* row = (const f32x4*)(inp + (size_t)b * D_DIM);
        f32x4 x = row[t], y = row[256 + t];
        float ss = x.x*x.x + x.y*x.y + x.z*x.z + x.w*x.w
                 + y.x*y.x + y.y*y.y + y.z*y.z + y.w*y.w;
        for (int o = 32; o > 0; o >>= 1) ss += __shfl_down(ss, o);
        __shared__ float wsum[4];
        if ((t & 63) == 0) wsum[t >> 6] = ss;
        __syncthreads();
        float inv = rsqrtf(wsum[0] + wsum[1] + wsum[2] + wsum[3]);
        ushort4 u0 = make_ushort4(f2bf(x.x*inv), f2bf(x.y*inv), f2bf(x.z*inv), f2bf(x.w*inv));
        ushort4 u1 = make_ushort4(f2bf(y.x*inv), f2bf(y.y*inv), f2bf(y.z*inv), f2bf(y.w*inv));
        *(ushort4*)(X + (size_t)b * D_DIM + 4*t)        = u0;
        *(ushort4*)(X + (size_t)b * D_DIM + 1024 + 4*t) = u1;
    }
    grid.sync();

    // ---- phase 1: label histogram ----
    int lab = labels[g];
    atomicAdd(&counts[lab], 1);
    grid.sync();

    // ---- phase 2: exclusive scan of 8192 counts (block 0 only) ----
    if (b == 0) {
        __shared__ int spart[256];
        int local[32];
        int s = 0;
        #pragma unroll
        for (int i = 0; i < 32; ++i) { local[i] = counts[t * 32 + i]; s += local[i]; }
        spart[t] = s;
        __syncthreads();
        int acc = s;
        for (int o = 1; o < 256; o <<= 1) {
            int v = (t >= o) ? spart[t - o] : 0;
            __syncthreads();
            acc += v;
            spart[t] = acc;
            __syncthreads();
        }
        int off = acc - s;   // exclusive prefix for class t*32
        #pragma unroll
        for (int i = 0; i < 32; ++i) {
            offsets[t * 32 + i] = off;
            cursor[t * 32 + i]  = off;
            off += local[i];
        }
    }
    grid.sync();

    // ---- phase 3: scatter inverted index ----
    int p = atomicAdd(&cursor[lab], 1);
    rowidx[p] = g;
}

// ============ per-class feature mean, scaled by 1/(T*n), to bf16 ============
__global__ __launch_bounds__(256) void k_class_mean(const float* __restrict__ feat,
                                                    const int* __restrict__ rowidx,
                                                    const int* __restrict__ offsets,
                                                    const int* __restrict__ counts,
                                                    unsigned short* __restrict__ G) {
    int c = blockIdx.x;
    int n = counts[c];
    int off = offsets[c];
    int t = threadIdx.x;
    f32x4 a = {0.f,0.f,0.f,0.f}, b = {0.f,0.f,0.f,0.f};
    int i = 0;
    for (; i + 3 < n; i += 4) {   // 4 rows in flight for memory-level parallelism
        int r0 = rowidx[off + i],     r1 = rowidx[off + i + 1];
        int r2 = rowidx[off + i + 2], r3 = rowidx[off + i + 3];
        const f32x4* p0 = (const f32x4*)(feat + (size_t)r0 * D_DIM);
        const f32x4* p1 = (const f32x4*)(feat + (size_t)r1 * D_DIM);
        const f32x4* p2 = (const f32x4*)(feat + (size_t)r2 * D_DIM);
        const f32x4* p3 = (const f32x4*)(feat + (size_t)r3 * D_DIM);
        f32x4 x0 = __builtin_nontemporal_load(p0 + t),       y0 = __builtin_nontemporal_load(p0 + 256 + t);
        f32x4 x1 = __builtin_nontemporal_load(p1 + t),       y1 = __builtin_nontemporal_load(p1 + 256 + t);
        f32x4 x2 = __builtin_nontemporal_load(p2 + t),       y2 = __builtin_nontemporal_load(p2 + 256 + t);
        f32x4 x3 = __builtin_nontemporal_load(p3 + t),       y3 = __builtin_nontemporal_load(p3 + 256 + t);
        a += (x0 + x1) + (x2 + x3);
        b += (y0 + y1) + (y2 + y3);
    }
    for (; i < n; ++i) {
        const f32x4* p0 = (const f32x4*)(feat + (size_t)rowidx[off + i] * D_DIM);
        a += __builtin_nontemporal_load(p0 + t);
        b += __builtin_nontemporal_load(p0 + 256 + t);
    }
    float s = (n > 0) ? (TEMP_INV / (float)n) : 0.0f;
    a *= s; b *= s;
    ushort4 u0 = make_ushort4(f2bf(a.x), f2bf(a.y), f2bf(a.z), f2bf(a.w));
    ushort4 u1 = make_ushort4(f2bf(b.x), f2bf(b.y), f2bf(b.z), f2bf(b.w));
    *(ushort4*)(G + (size_t)c * D_DIM + 4*t)        = u0;
    *(ushort4*)(G + (size_t)c * D_DIM + 1024 + 4*t) = u1;
}

// ============ sim = X @ G^T, direct-from-L2 register GEMM, split-K=2 ============
// 1024 blocks x 64 threads (1 wave). Each wave: 64x64 output tile, K-half zi.
// No LDS, no barriers: fragments stream from L2 (X is 1MB, G-slices L2-resident
// via XCD-chunked block assignment). 2-set register ping-pong hides L2 latency.
__global__ __launch_bounds__(64) void k_gemm(const unsigned short* __restrict__ X,
                                             const unsigned short* __restrict__ G,
                                             float* __restrict__ simp) {
    int bid = blockIdx.x;
    int lin = (bid & 7) * 128 + (bid >> 3);    // XCD x owns lin in [128x, 128x+128)
    int tile = lin >> 1;                       // 0..511
    int zi   = lin & 1;                        // K half
    int ct = tile >> 2, rt = tile & 3;         // 128 col tiles x 4 row tiles
    int bc0 = ct * 64, br0 = rt * 64;

    int lane = threadIdx.x;
    int fr = lane & 15;
    int fk = (lane >> 4) * 8;
    size_t k0 = (size_t)zi * 1024;

    const unsigned short* Ab = X + (size_t)(br0 + fr) * D_DIM + k0 + fk;
    const unsigned short* Bb = G + (size_t)(bc0 + fr) * D_DIM + k0 + fk;

    f32x4 acc[4][4];
    #pragma unroll
    for (int i = 0; i < 4; ++i)
        #pragma unroll
        for (int j = 0; j < 4; ++j) acc[i][j] = (f32x4){0.f, 0.f, 0.f, 0.f};

    short8 aA[8], bA[8], aB[8], bB[8];   // two named sets (static indexing only)

    auto loadset = [&](short8* a, short8* bf, int t) {
        #pragma unroll
        for (int kk = 0; kk < 2; ++kk) {
            size_t cb = (size_t)t * 64 + kk * 32;
            #pragma unroll
            for (int mi = 0; mi < 4; ++mi)
                a[kk*4+mi] = *(const short8*)(Ab + (size_t)mi * 16 * D_DIM + cb);
            #pragma unroll
            for (int ni = 0; ni < 4; ++ni)
                bf[kk*4+ni] = *(const short8*)(Bb + (size_t)ni * 16 * D_DIM + cb);
        }
    };
    auto compute = [&](const short8* a, const short8* bf) {
        #pragma unroll
        for (int kk = 0; kk < 2; ++kk)
            #pragma unroll
            for (int mi = 0; mi < 4; ++mi)
                #pragma unroll
                for (int ni = 0; ni < 4; ++ni)
                    acc[mi][ni] = __builtin_amdgcn_mfma_f32_16x16x32_bf16(
                        a[kk*4+mi], bf[kk*4+ni], acc[mi][ni], 0, 0, 0);
    };

    loadset(aA, bA, 0);
    #pragma unroll 1
    for (int t = 0; t < 16; t += 2) {          // 16 BK=64 steps, ping-pong
        loadset(aB, bB, t + 1);
        compute(aA, bA);
        if (t + 2 < 16) loadset(aA, bA, t + 2);
        compute(aB, bB);
    }

    float* outp = simp + (size_t)zi * B_ROWS * C_CLASSES;
    #pragma unroll
    for (int mi = 0; mi < 4; ++mi) {
        int row = br0 + mi * 16 + (lane >> 4) * 4;
        #pragma unroll
        for (int ni = 0; ni < 4; ++ni) {
            int col = bc0 + ni * 16 + fr;
            #pragma unroll
            for (int r = 0; r < 4; ++r)
                outp[(size_t)(row + r) * C_CLASSES + col] = acc[mi][ni][r];
        }
    }
}

// ============ masked softmax denom + NLL (sums the two split-K partials) ============
__global__ __launch_bounds__(256) void k_loss(const float* __restrict__ simp,
                                              const int* __restrict__ counts,
                                              const int* __restrict__ labels,
                                              const int* __restrict__ idx,
                                              float* __restrict__ out) {
    int b = blockIdx.x, t = threadIdx.x;
    const float* row0 = simp + (size_t)b * C_CLASSES;
    const float* row1 = row0 + (size_t)B_ROWS * C_CLASSES;
    const f32x4* r0 = (const f32x4*)row0;
    const f32x4* r1 = (const f32x4*)row1;
    const int4*  cnt4 = (const int4*)counts;
    float s = 0.f;
    for (int j = t; j < C_CLASSES / 4; j += 256) {
        f32x4 v = r0[j] + r1[j];
        int4  c = cnt4[j];
        if (c.x > 0) s += expf(v.x);
        if (c.y > 0) s += expf(v.y);
        if (c.z > 0) s += expf(v.z);
        if (c.w > 0) s += expf(v.w);
    }
    for (int o = 32; o > 0; o >>= 1) s += __shfl_down(s, o);
    __shared__ float wsum[4];
    if ((t & 63) == 0) wsum[t >> 6] = s;
    __syncthreads();
    if (t == 0) {
        float total = wsum[0] + wsum[1] + wsum[2] + wsum[3];
        int target = labels[idx[b]];                 // target class is never empty
        float p = expf(row0[target] + row1[target]) / (total + 1e-6f);
        atomicAdd(out, -logf(p + 1e-6f) * (1.0f / 256.0f));
    }
}

extern "C" void kernel_launch(void* const* d_in, const int* in_sizes, int n_in,
                              void* d_out, int out_size, void* d_ws, size_t ws_size,
                              hipStream_t stream) {
    const float* inputs = (const float*)d_in[0];
    const float* feats  = (const float*)d_in[1];
    const int*   labels = (const int*)d_in[2];
    const int*   idx    = (const int*)d_in[3];
    float* out = (float*)d_out;

    char* p = (char*)d_ws;
    auto alloc = [&](size_t bytes) { char* r = p; p += (bytes + 255) & ~(size_t)255; return r; };
    int* counts   = (int*)alloc((size_t)C_CLASSES * 4);
    int* offsets  = (int*)alloc((size_t)C_CLASSES * 4);
    int* cursor   = (int*)alloc((size_t)C_CLASSES * 4);
    int* rowidx   = (int*)alloc((size_t)M_ROWS * 4);
    unsigned short* Xb = (unsigned short*)alloc((size_t)B_ROWS * D_DIM * 2);
    unsigned short* Gb = (unsigned short*)alloc((size_t)C_CLASSES * D_DIM * 2);
    float* simp = (float*)alloc((size_t)2 * B_ROWS * C_CLASSES * 4);   // split-K partials

    void* args[] = {(void*)&labels, (void*)&inputs, (void*)&counts, (void*)&offsets,
                    (void*)&cursor, (void*)&rowidx, (void*)&Xb, (void*)&out};
    hipLaunchCooperativeKernel(reinterpret_cast<void*>(k_prelude),
                               dim3(B_ROWS), dim3(256), args, 0, stream);
    k_class_mean<<<C_CLASSES, 256, 0, stream>>>(feats, rowidx, offsets, counts, Gb);
    k_gemm<<<1024, 64, 0, stream>>>(Xb, Gb, simp);
    k_loss<<<B_ROWS, 256, 0, stream>>>(simp, counts, labels, idx, out);
}

// Round 4
// 154.410 us; speedup vs baseline: 1.6331x; 1.6331x over previous
//
#include <hip/hip_runtime.h>
#include <hip/hip_bf16.h>

#define C_CLASSES 8192
#define M_ROWS    65536
#define B_ROWS    256
#define D_DIM     2048
#define TEMP_INV  20.0f   // 1 / 0.05

typedef __attribute__((ext_vector_type(8))) short short8;   // 8 bf16 (4 VGPRs)
typedef __attribute__((ext_vector_type(4))) float f32x4;    // MFMA accumulator / vec4

static __device__ __forceinline__ unsigned short f2bf(float x) {
    __hip_bfloat16 h = __float2bfloat16(x);
    return *reinterpret_cast<unsigned short*>(&h);
}

// async global->LDS, 16B per lane; LDS dest = wave-uniform base + lane*16
static __device__ __forceinline__ void gload16(const void* g, void* l) {
    __builtin_amdgcn_global_load_lds((const __attribute__((address_space(1))) void*)g,
                                     (__attribute__((address_space(3))) void*)l, 16, 0, 0);
}

// ---------------- histogram of labels + L2-normalize inputs (fused) ----------------
__global__ __launch_bounds__(256) void k_hist_norm(const int* __restrict__ labels,
                                                   int* __restrict__ counts,
                                                   const float* __restrict__ inp,
                                                   unsigned short* __restrict__ X) {
    int b = blockIdx.x, t = threadIdx.x;
    atomicAdd(&counts[labels[b * 256 + t]], 1);

    const f32x4* row = (const f32x4*)(inp + (size_t)b * D_DIM);
    f32x4 x = row[t], y = row[256 + t];
    float ss = x.x*x.x + x.y*x.y + x.z*x.z + x.w*x.w
             + y.x*y.x + y.y*y.y + y.z*y.z + y.w*y.w;
    for (int o = 32; o > 0; o >>= 1) ss += __shfl_down(ss, o);
    __shared__ float wsum[4];
    if ((t & 63) == 0) wsum[t >> 6] = ss;
    __syncthreads();
    float inv = rsqrtf(wsum[0] + wsum[1] + wsum[2] + wsum[3]);
    ushort4 u0 = make_ushort4(f2bf(x.x*inv), f2bf(x.y*inv), f2bf(x.z*inv), f2bf(x.w*inv));
    ushort4 u1 = make_ushort4(f2bf(y.x*inv), f2bf(y.y*inv), f2bf(y.z*inv), f2bf(y.w*inv));
    *(ushort4*)(X + (size_t)b * D_DIM + 4*t)        = u0;
    *(ushort4*)(X + (size_t)b * D_DIM + 1024 + 4*t) = u1;
}

// ---------------- exclusive scan over 8192 counts (1 block) + zero the output ----------------
__global__ __launch_bounds__(256) void k_scan(const int* __restrict__ counts,
                                              int* __restrict__ offsets,
                                              int* __restrict__ cursor,
                                              float* __restrict__ out) {
    __shared__ int part[256];
    int t = threadIdx.x;
    int local[32];
    int s = 0;
    #pragma unroll
    for (int i = 0; i < 32; ++i) { local[i] = counts[t * 32 + i]; s += local[i]; }
    part[t] = s;
    __syncthreads();
    if (t == 0) {
        int acc = 0;
        for (int i = 0; i < 256; ++i) { int v = part[i]; part[i] = acc; acc += v; }
        out[0] = 0.0f;   // k_loss accumulates atomically into this
    }
    __syncthreads();
    int off = part[t];
    #pragma unroll
    for (int i = 0; i < 32; ++i) {
        offsets[t * 32 + i] = off;
        cursor[t * 32 + i]  = off;
        off += local[i];
    }
}

// ---------------- scatter: build inverted index ----------------
__global__ void k_scatter(const int* __restrict__ labels, int* __restrict__ cursor,
                          int* __restrict__ rowidx) {
    int m = blockIdx.x * 256 + threadIdx.x;
    int c = labels[m];
    int p = atomicAdd(&cursor[c], 1);
    rowidx[p] = m;
}

// ---------------- per-class feature mean, scaled by 1/(T*n), to bf16 ----------------
__global__ __launch_bounds__(256) void k_class_mean(const float* __restrict__ feat,
                                                    const int* __restrict__ rowidx,
                                                    const int* __restrict__ offsets,
                                                    const int* __restrict__ counts,
                                                    unsigned short* __restrict__ G) {
    int c = blockIdx.x;
    int n = counts[c];
    int off = offsets[c];
    int t = threadIdx.x;
    f32x4 a = {0.f,0.f,0.f,0.f}, b = {0.f,0.f,0.f,0.f};
    int i = 0;
    for (; i + 1 < n; i += 2) {   // 2 rows in flight for memory-level parallelism
        const f32x4* p0 = (const f32x4*)(feat + (size_t)rowidx[off + i]     * D_DIM);
        const f32x4* p1 = (const f32x4*)(feat + (size_t)rowidx[off + i + 1] * D_DIM);
        f32x4 x0 = __builtin_nontemporal_load(p0 + t);
        f32x4 y0 = __builtin_nontemporal_load(p0 + 256 + t);
        f32x4 x1 = __builtin_nontemporal_load(p1 + t);
        f32x4 y1 = __builtin_nontemporal_load(p1 + 256 + t);
        a += x0 + x1;
        b += y0 + y1;
    }
    if (i < n) {
        const f32x4* p0 = (const f32x4*)(feat + (size_t)rowidx[off + i] * D_DIM);
        a += __builtin_nontemporal_load(p0 + t);
        b += __builtin_nontemporal_load(p0 + 256 + t);
    }
    float s = (n > 0) ? (TEMP_INV / (float)n) : 0.0f;
    a *= s; b *= s;
    ushort4 u0 = make_ushort4(f2bf(a.x), f2bf(a.y), f2bf(a.z), f2bf(a.w));
    ushort4 u1 = make_ushort4(f2bf(b.x), f2bf(b.y), f2bf(b.z), f2bf(b.w));
    *(ushort4*)(G + (size_t)c * D_DIM + 4*t)        = u0;
    *(ushort4*)(G + (size_t)c * D_DIM + 1024 + 4*t) = u1;
}

// ---------------- sim = X @ G^T (bf16 MFMA, fp32 accum), split-K=2 ----------------
// 64x64 tile, BK=64, 1024 blocks (4/CU, 16 waves/CU), global_load_lds w=16 with
// pre-swizzled source, LDS double-buffer, stage-before-MFMA. XCD-chunked so each
// XCD reads a 4MB slice of G (fits its private L2) and all of X (1MB).
__global__ __launch_bounds__(256) void k_gemm(const unsigned short* __restrict__ X,
                                              const unsigned short* __restrict__ G,
                                              float* __restrict__ simp) {
    __shared__ unsigned short As[2][64 * 64];
    __shared__ unsigned short Bs[2][64 * 64];
    int tid = threadIdx.x;
    int bid = blockIdx.x;                       // 0..1023
    int lin = (bid & 7) * 128 + (bid >> 3);     // XCD-chunked (1024 % 8 == 0, bijective)
    int tile = lin >> 1;                        // 0..511 (consecutive pair on same XCD)
    int zi   = lin & 1;                         // K half
    int ct = tile >> 2, rt = tile & 3;          // 128 col tiles x 4 row tiles
    int bc0 = ct * 64;                          // class tile base
    int br0 = rt * 64;                          // batch-row tile base
    int kbase = zi * (D_DIM / 2);

    int lane = tid & 63, wave = tid >> 6;
    int wm = wave >> 1, wn = wave & 1;          // 2x2 wave grid, 32x32 per wave
    int fr = lane & 15;
    int fkb = (lane >> 4) << 4;                 // byte offset of 8-elem k-fragment
    int rowl = lane >> 3;                       // 0..7: row within 1KB lane-block
    int colsw = ((lane & 7) ^ rowl) << 3;       // pre-swizzled source col (elems)

    f32x4 acc[2][2];
    #pragma unroll
    for (int i = 0; i < 2; ++i)
        #pragma unroll
        for (int j = 0; j < 2; ++j) acc[i][j] = (f32x4){0.f, 0.f, 0.f, 0.f};

    // stage one 64x64 K-tile of A and B into LDS buffer `buf` (async)
    auto stage = [&](int buf, int k0) {
        #pragma unroll
        for (int it = 0; it < 2; ++it) {
            int row = wave * 8 + it * 32 + rowl;
            gload16(X + (size_t)(br0 + row) * D_DIM + k0 + colsw,
                    &As[buf][wave * 512 + it * 2048]);
            gload16(G + (size_t)(bc0 + row) * D_DIM + k0 + colsw,
                    &Bs[buf][wave * 512 + it * 2048]);
        }
    };

    stage(0, kbase);
    int cur = 0;
    const int NT = (D_DIM / 2) / 64;   // 16 K-steps per split-K half
    for (int t = 0; t < NT; ++t) {
        asm volatile("s_waitcnt vmcnt(0)" ::: "memory");
        __syncthreads();                         // buf[cur] ready for all waves
        if (t + 1 < NT) stage(cur ^ 1, kbase + (t + 1) * 64);   // prefetch overlaps MFMA

        short8 af[2][2], bg[2][2];
        #pragma unroll
        for (int kk = 0; kk < 2; ++kk) {
            int cb = (kk * 64 + fkb) ^ ((fr & 7) << 4);   // swizzled byte col
            #pragma unroll
            for (int mi = 0; mi < 2; ++mi) {
                int row = wm * 32 + mi * 16 + fr;
                af[mi][kk] = *(const short8*)((const char*)As[cur] + row * 128 + cb);
            }
            #pragma unroll
            for (int ni = 0; ni < 2; ++ni) {
                int row = wn * 32 + ni * 16 + fr;
                bg[ni][kk] = *(const short8*)((const char*)Bs[cur] + row * 128 + cb);
            }
        }
        #pragma unroll
        for (int kk = 0; kk < 2; ++kk)
            #pragma unroll
            for (int mi = 0; mi < 2; ++mi)
                #pragma unroll
                for (int ni = 0; ni < 2; ++ni)
                    acc[mi][ni] = __builtin_amdgcn_mfma_f32_16x16x32_bf16(
                        af[mi][kk], bg[ni][kk], acc[mi][ni], 0, 0, 0);
        cur ^= 1;
    }

    float* outp = simp + (size_t)zi * B_ROWS * C_CLASSES;
    #pragma unroll
    for (int mi = 0; mi < 2; ++mi) {
        int row = br0 + wm * 32 + mi * 16 + (lane >> 4) * 4;
        #pragma unroll
        for (int ni = 0; ni < 2; ++ni) {
            int col = bc0 + wn * 32 + ni * 16 + fr;
            #pragma unroll
            for (int r = 0; r < 4; ++r)
                outp[(size_t)(row + r) * C_CLASSES + col] = acc[mi][ni][r];
        }
    }
}

// ---------------- masked softmax denom + NLL (sums the two split-K partials) ----------------
__global__ __launch_bounds__(256) void k_loss(const float* __restrict__ simp,
                                              const int* __restrict__ counts,
                                              const int* __restrict__ labels,
                                              const int* __restrict__ idx,
                                              float* __restrict__ out) {
    int b = blockIdx.x, t = threadIdx.x;
    const float* row0 = simp + (size_t)b * C_CLASSES;
    const float* row1 = row0 + (size_t)B_ROWS * C_CLASSES;
    const f32x4* r0 = (const f32x4*)row0;
    const f32x4* r1 = (const f32x4*)row1;
    const int4*  cnt4 = (const int4*)counts;
    float s = 0.f;
    for (int j = t; j < C_CLASSES / 4; j += 256) {
        f32x4 v = r0[j] + r1[j];
        int4  c = cnt4[j];
        if (c.x > 0) s += expf(v.x);
        if (c.y > 0) s += expf(v.y);
        if (c.z > 0) s += expf(v.z);
        if (c.w > 0) s += expf(v.w);
    }
    for (int o = 32; o > 0; o >>= 1) s += __shfl_down(s, o);
    __shared__ float wsum[4];
    if ((t & 63) == 0) wsum[t >> 6] = s;
    __syncthreads();
    if (t == 0) {
        float total = wsum[0] + wsum[1] + wsum[2] + wsum[3];
        int target = labels[idx[b]];                 // target class is never empty
        float p = expf(row0[target] + row1[target]) / (total + 1e-6f);
        atomicAdd(out, -logf(p + 1e-6f) * (1.0f / 256.0f));
    }
}

extern "C" void kernel_launch(void* const* d_in, const int* in_sizes, int n_in,
                              void* d_out, int out_size, void* d_ws, size_t ws_size,
                              hipStream_t stream) {
    const float* inputs = (const float*)d_in[0];
    const float* feats  = (const float*)d_in[1];
    const int*   labels = (const int*)d_in[2];
    const int*   idx    = (const int*)d_in[3];
    float* out = (float*)d_out;

    char* p = (char*)d_ws;
    auto alloc = [&](size_t bytes) { char* r = p; p += (bytes + 255) & ~(size_t)255; return r; };
    int* counts   = (int*)alloc((size_t)C_CLASSES * 4);
    int* offsets  = (int*)alloc((size_t)C_CLASSES * 4);
    int* cursor   = (int*)alloc((size_t)C_CLASSES * 4);
    int* rowidx   = (int*)alloc((size_t)M_ROWS * 4);
    unsigned short* Xb = (unsigned short*)alloc((size_t)B_ROWS * D_DIM * 2);
    unsigned short* Gb = (unsigned short*)alloc((size_t)C_CLASSES * D_DIM * 2);
    float* simp = (float*)alloc((size_t)2 * B_ROWS * C_CLASSES * 4);   // split-K partials

    hipMemsetAsync(counts, 0, (size_t)C_CLASSES * 4, stream);
    k_hist_norm<<<B_ROWS, 256, 0, stream>>>(labels, counts, inputs, Xb);
    k_scan<<<1, 256, 0, stream>>>(counts, offsets, cursor, out);
    k_scatter<<<M_ROWS / 256, 256, 0, stream>>>(labels, cursor, rowidx);
    k_class_mean<<<C_CLASSES, 256, 0, stream>>>(feats, rowidx, offsets, counts, Gb);
    k_gemm<<<1024, 256, 0, stream>>>(Xb, Gb, simp);
    k_loss<<<B_ROWS, 256, 0, stream>>>(simp, counts, labels, idx, out);
}